// Round 1
// baseline (433.317 us; speedup 1.0000x reference)
//
#include <hip/hip_runtime.h>

#define EPS 1e-4f
#define FRAMES 4000
#define TPB 256
#define VPT 4                      // float4 per thread
#define EPT (VPT * 4)              // 16 elements per thread
#define ACTIVE_T (FRAMES / EPT)    // 250 active threads per row

// One block (256 threads, 4 waves) per row. Each thread owns 16 contiguous
// elements (4 float4). Single-pass hierarchical scan:
//   per-thread serial totals -> wave shfl-scan of thread totals ->
//   LDS exchange of 4 wave totals -> per-thread output epilogue.
// Only ONE load round-trip and ONE shuffle-scan per wave per row, vs. 16
// serially-dependent chunk iterations in the previous version.
__global__ __launch_bounds__(TPB) void cumnorm_kernel(const float* __restrict__ x,
                                                      float* __restrict__ out,
                                                      int rows) {
    const int row  = blockIdx.x;
    if (row >= rows) return;
    const int t    = threadIdx.x;
    const int wave = t >> 6;
    const int lane = t & 63;

    const float4* __restrict__ xr = (const float4*)(x + (size_t)row * FRAMES);
    float4* __restrict__ outr     = (float4*)(out + (size_t)row * FRAMES);

    const bool active = (t < ACTIVE_T);

    // ---- 1. load all 16 elements upfront (4 independent dwordx4 loads) ----
    float4 v[VPT];
    if (active) {
        #pragma unroll
        for (int j = 0; j < VPT; ++j) v[j] = xr[t * VPT + j];
    } else {
        #pragma unroll
        for (int j = 0; j < VPT; ++j) v[j] = make_float4(0.f, 0.f, 0.f, 0.f);
    }

    // ---- 2. per-thread totals (sum and sum of squares) ----
    float S = 0.f, Q = 0.f;
    #pragma unroll
    for (int j = 0; j < VPT; ++j) {
        S += v[j].x; Q = fmaf(v[j].x, v[j].x, Q);
        S += v[j].y; Q = fmaf(v[j].y, v[j].y, Q);
        S += v[j].z; Q = fmaf(v[j].z, v[j].z, Q);
        S += v[j].w; Q = fmaf(v[j].w, v[j].w, Q);
    }

    // ---- 3. wave-inclusive scan of thread totals (6 shfl levels) ----
    float ss = S, qq = Q;
    #pragma unroll
    for (int d = 1; d < 64; d <<= 1) {
        const float us = __shfl_up(ss, d, 64);
        const float uq = __shfl_up(qq, d, 64);
        if (lane >= d) { ss += us; qq += uq; }
    }

    // ---- 4. cross-wave scan via LDS (4 wave totals) ----
    __shared__ float wsum[4];
    __shared__ float wsq[4];
    if (lane == 63) { wsum[wave] = ss; wsq[wave] = qq; }
    __syncthreads();

    float cs = ss - S;   // intra-wave exclusive prefix
    float cq = qq - Q;
    #pragma unroll
    for (int w = 0; w < 3; ++w) {
        if (w < wave) { cs += wsum[w]; cq += wsq[w]; }
    }

    // ---- 5. output epilogue: per-element running stats in registers ----
    if (active) {
        const float nbase = (float)(t * EPT);
        #pragma unroll
        for (int j = 0; j < VPT; ++j) {
            float4 r;
            {
                cs += v[j].x; cq = fmaf(v[j].x, v[j].x, cq);
                const float inv  = __builtin_amdgcn_rcpf(nbase + (float)(j * 4 + 1));
                const float mean = cs * inv;
                const float var  = fmaf(-mean, mean, cq * inv);
                r.x = (v[j].x - mean) * __builtin_amdgcn_rsqf(var + EPS);
            }
            {
                cs += v[j].y; cq = fmaf(v[j].y, v[j].y, cq);
                const float inv  = __builtin_amdgcn_rcpf(nbase + (float)(j * 4 + 2));
                const float mean = cs * inv;
                const float var  = fmaf(-mean, mean, cq * inv);
                r.y = (v[j].y - mean) * __builtin_amdgcn_rsqf(var + EPS);
            }
            {
                cs += v[j].z; cq = fmaf(v[j].z, v[j].z, cq);
                const float inv  = __builtin_amdgcn_rcpf(nbase + (float)(j * 4 + 3));
                const float mean = cs * inv;
                const float var  = fmaf(-mean, mean, cq * inv);
                r.z = (v[j].z - mean) * __builtin_amdgcn_rsqf(var + EPS);
            }
            {
                cs += v[j].w; cq = fmaf(v[j].w, v[j].w, cq);
                const float inv  = __builtin_amdgcn_rcpf(nbase + (float)(j * 4 + 4));
                const float mean = cs * inv;
                const float var  = fmaf(-mean, mean, cq * inv);
                r.w = (v[j].w - mean) * __builtin_amdgcn_rsqf(var + EPS);
            }
            outr[t * VPT + j] = r;
        }
    }
}

extern "C" void kernel_launch(void* const* d_in, const int* in_sizes, int n_in,
                              void* d_out, int out_size, void* d_ws, size_t ws_size,
                              hipStream_t stream) {
    const float* x = (const float*)d_in[0];
    float* out = (float*)d_out;
    const int rows = in_sizes[0] / FRAMES;  // 32*512 = 16384

    dim3 grid(rows);
    dim3 block(TPB);
    cumnorm_kernel<<<grid, block, 0, stream>>>(x, out, rows);
}

// Round 2
// 423.850 us; speedup vs baseline: 1.0223x; 1.0223x over previous
//
#include <hip/hip_runtime.h>

#define EPS 1e-4f
#define FRAMES 4000
#define TPB 256
#define NV (FRAMES / 4)        // 1000 float4 per row
#define NCHUNK 4               // chunks of 256 vec4: 256,256,256,232
#define LAST_ACT (NV - 3 * TPB) // 232 active threads in chunk 3

// One block (256 threads, 4 waves) per row, CYCLIC vec4 ownership:
// thread t owns vec4 positions {t, 256+t, 512+t, 768+t}. Every global
// load/store is per-instruction coalesced (64 lanes x 16B contiguous).
// Scan: per-vec4 serial -> 4 independent wave-scans of thread totals
// (ILP across chunks) -> one 32-float LDS exchange + one barrier ->
// register epilogue.
__global__ __launch_bounds__(TPB) void cumnorm_kernel(const float* __restrict__ x,
                                                      float* __restrict__ out,
                                                      int rows) {
    const int row  = blockIdx.x;
    if (row >= rows) return;
    const int t    = threadIdx.x;
    const int wave = t >> 6;
    const int lane = t & 63;

    const float4* __restrict__ xr = (const float4*)(x + (size_t)row * FRAMES);
    float4* __restrict__ outr     = (float4*)(out + (size_t)row * FRAMES);

    const bool act3 = (t < LAST_ACT);

    // ---- 1. coalesced loads: 4 x (64 lanes x 16B contiguous) ----
    float4 v[NCHUNK];
    v[0] = xr[t];
    v[1] = xr[TPB + t];
    v[2] = xr[2 * TPB + t];
    v[3] = act3 ? xr[3 * TPB + t] : make_float4(0.f, 0.f, 0.f, 0.f);

    // ---- 2. per-thread chunk totals ----
    float S[NCHUNK], Q[NCHUNK];
    #pragma unroll
    for (int k = 0; k < NCHUNK; ++k) {
        float s = v[k].x;            float q = v[k].x * v[k].x;
        s += v[k].y;                 q = fmaf(v[k].y, v[k].y, q);
        s += v[k].z;                 q = fmaf(v[k].z, v[k].z, q);
        s += v[k].w;                 q = fmaf(v[k].w, v[k].w, q);
        S[k] = s; Q[k] = q;
    }

    // ---- 3. four independent wave-inclusive scans (ILP across chunks) ----
    float ss[NCHUNK], qq[NCHUNK];
    #pragma unroll
    for (int k = 0; k < NCHUNK; ++k) { ss[k] = S[k]; qq[k] = Q[k]; }
    #pragma unroll
    for (int d = 1; d < 64; d <<= 1) {
        float us[NCHUNK], uq[NCHUNK];
        #pragma unroll
        for (int k = 0; k < NCHUNK; ++k) {
            us[k] = __shfl_up(ss[k], d, 64);
            uq[k] = __shfl_up(qq[k], d, 64);
        }
        if (lane >= d) {
            #pragma unroll
            for (int k = 0; k < NCHUNK; ++k) { ss[k] += us[k]; qq[k] += uq[k]; }
        }
    }

    // ---- 4. cross-wave + cross-chunk via tiny LDS exchange ----
    __shared__ float wt_s[NCHUNK][4];
    __shared__ float wt_q[NCHUNK][4];
    if (lane == 63) {
        #pragma unroll
        for (int k = 0; k < NCHUNK; ++k) { wt_s[k][wave] = ss[k]; wt_q[k][wave] = qq[k]; }
    }
    __syncthreads();

    float excl_s[NCHUNK], excl_q[NCHUNK];
    {
        float carry_s = 0.f, carry_q = 0.f;
        #pragma unroll
        for (int k = 0; k < NCHUNK; ++k) {
            float wp_s = 0.f, wp_q = 0.f, ct_s = 0.f, ct_q = 0.f;
            #pragma unroll
            for (int w = 0; w < 4; ++w) {
                const float a = wt_s[k][w], b = wt_q[k][w];   // broadcast reads
                ct_s += a; ct_q += b;
                if (w < wave) { wp_s += a; wp_q += b; }
            }
            excl_s[k] = carry_s + wp_s + (ss[k] - S[k]);
            excl_q[k] = carry_q + wp_q + (qq[k] - Q[k]);
            carry_s += ct_s; carry_q += ct_q;
        }
    }

    // ---- 5. register epilogue + coalesced stores ----
    #pragma unroll
    for (int k = 0; k < NCHUNK; ++k) {
        if (k == 3 && !act3) break;
        float cs = excl_s[k], cq = excl_q[k];
        const float nbase = (float)((k * TPB + t) << 2);
        float4 r;
        {
            cs += v[k].x; cq = fmaf(v[k].x, v[k].x, cq);
            const float inv  = __builtin_amdgcn_rcpf(nbase + 1.0f);
            const float mean = cs * inv;
            const float var  = fmaf(-mean, mean, cq * inv);
            r.x = (v[k].x - mean) * __builtin_amdgcn_rsqf(var + EPS);
        }
        {
            cs += v[k].y; cq = fmaf(v[k].y, v[k].y, cq);
            const float inv  = __builtin_amdgcn_rcpf(nbase + 2.0f);
            const float mean = cs * inv;
            const float var  = fmaf(-mean, mean, cq * inv);
            r.y = (v[k].y - mean) * __builtin_amdgcn_rsqf(var + EPS);
        }
        {
            cs += v[k].z; cq = fmaf(v[k].z, v[k].z, cq);
            const float inv  = __builtin_amdgcn_rcpf(nbase + 3.0f);
            const float mean = cs * inv;
            const float var  = fmaf(-mean, mean, cq * inv);
            r.z = (v[k].z - mean) * __builtin_amdgcn_rsqf(var + EPS);
        }
        {
            cs += v[k].w; cq = fmaf(v[k].w, v[k].w, cq);
            const float inv  = __builtin_amdgcn_rcpf(nbase + 4.0f);
            const float mean = cs * inv;
            const float var  = fmaf(-mean, mean, cq * inv);
            r.w = (v[k].w - mean) * __builtin_amdgcn_rsqf(var + EPS);
        }
        outr[k * TPB + t] = r;
    }
}

extern "C" void kernel_launch(void* const* d_in, const int* in_sizes, int n_in,
                              void* d_out, int out_size, void* d_ws, size_t ws_size,
                              hipStream_t stream) {
    const float* x = (const float*)d_in[0];
    float* out = (float*)d_out;
    const int rows = in_sizes[0] / FRAMES;  // 32*512 = 16384

    cumnorm_kernel<<<dim3(rows), dim3(TPB), 0, stream>>>(x, out, rows);
}

// Round 4
// 402.123 us; speedup vs baseline: 1.0776x; 1.0540x over previous
//
#include <hip/hip_runtime.h>

#define EPS 1e-4f
#define FRAMES 4000
#define TPB 256
#define NV (FRAMES / 4)        // 1000 float4 per row
#define NCHUNK 4               // chunks of 256 vec4: 256,256,256,232
#define LAST_ACT (NV - 3 * TPB) // 232 active threads in chunk 3

typedef float f4 __attribute__((ext_vector_type(4)));  // native vector: OK for nontemporal builtins

// One block (256 threads, 4 waves) per row, CYCLIC vec4 ownership:
// thread t owns vec4 positions {t, 256+t, 512+t, 768+t}. Every global
// load/store is per-instruction coalesced (64 lanes x 16B contiguous).
// Scan: per-vec4 serial -> 4 independent wave-scans of thread totals
// (ILP across chunks) -> one 32-float LDS exchange + one barrier ->
// register epilogue.
// R4 = R3 retry: nontemporal loads+stores via ext_vector_type(4)
// (HIP float4 is a class type the builtin rejects).
__global__ __launch_bounds__(TPB) void cumnorm_kernel(const float* __restrict__ x,
                                                      float* __restrict__ out,
                                                      int rows) {
    const int row  = blockIdx.x;
    if (row >= rows) return;
    const int t    = threadIdx.x;
    const int wave = t >> 6;
    const int lane = t & 63;

    const f4* __restrict__ xr = (const f4*)(x + (size_t)row * FRAMES);
    f4* __restrict__ outr     = (f4*)(out + (size_t)row * FRAMES);

    const bool act3 = (t < LAST_ACT);

    // ---- 1. coalesced nontemporal loads: 4 x (64 lanes x 16B contiguous) ----
    f4 v[NCHUNK];
    v[0] = __builtin_nontemporal_load(xr + t);
    v[1] = __builtin_nontemporal_load(xr + TPB + t);
    v[2] = __builtin_nontemporal_load(xr + 2 * TPB + t);
    v[3] = act3 ? __builtin_nontemporal_load(xr + 3 * TPB + t) : (f4)(0.f);

    // ---- 2. per-thread chunk totals ----
    float S[NCHUNK], Q[NCHUNK];
    #pragma unroll
    for (int k = 0; k < NCHUNK; ++k) {
        float s = v[k].x;            float q = v[k].x * v[k].x;
        s += v[k].y;                 q = fmaf(v[k].y, v[k].y, q);
        s += v[k].z;                 q = fmaf(v[k].z, v[k].z, q);
        s += v[k].w;                 q = fmaf(v[k].w, v[k].w, q);
        S[k] = s; Q[k] = q;
    }

    // ---- 3. four independent wave-inclusive scans (ILP across chunks) ----
    float ss[NCHUNK], qq[NCHUNK];
    #pragma unroll
    for (int k = 0; k < NCHUNK; ++k) { ss[k] = S[k]; qq[k] = Q[k]; }
    #pragma unroll
    for (int d = 1; d < 64; d <<= 1) {
        float us[NCHUNK], uq[NCHUNK];
        #pragma unroll
        for (int k = 0; k < NCHUNK; ++k) {
            us[k] = __shfl_up(ss[k], d, 64);
            uq[k] = __shfl_up(qq[k], d, 64);
        }
        if (lane >= d) {
            #pragma unroll
            for (int k = 0; k < NCHUNK; ++k) { ss[k] += us[k]; qq[k] += uq[k]; }
        }
    }

    // ---- 4. cross-wave + cross-chunk via tiny LDS exchange ----
    __shared__ float wt_s[NCHUNK][4];
    __shared__ float wt_q[NCHUNK][4];
    if (lane == 63) {
        #pragma unroll
        for (int k = 0; k < NCHUNK; ++k) { wt_s[k][wave] = ss[k]; wt_q[k][wave] = qq[k]; }
    }
    __syncthreads();

    float excl_s[NCHUNK], excl_q[NCHUNK];
    {
        float carry_s = 0.f, carry_q = 0.f;
        #pragma unroll
        for (int k = 0; k < NCHUNK; ++k) {
            float wp_s = 0.f, wp_q = 0.f, ct_s = 0.f, ct_q = 0.f;
            #pragma unroll
            for (int w = 0; w < 4; ++w) {
                const float a = wt_s[k][w], b = wt_q[k][w];   // broadcast reads
                ct_s += a; ct_q += b;
                if (w < wave) { wp_s += a; wp_q += b; }
            }
            excl_s[k] = carry_s + wp_s + (ss[k] - S[k]);
            excl_q[k] = carry_q + wp_q + (qq[k] - Q[k]);
            carry_s += ct_s; carry_q += ct_q;
        }
    }

    // ---- 5. register epilogue + coalesced nontemporal stores ----
    #pragma unroll
    for (int k = 0; k < NCHUNK; ++k) {
        if (k == 3 && !act3) break;
        float cs = excl_s[k], cq = excl_q[k];
        const float nbase = (float)((k * TPB + t) << 2);
        f4 r;
        {
            cs += v[k].x; cq = fmaf(v[k].x, v[k].x, cq);
            const float inv  = __builtin_amdgcn_rcpf(nbase + 1.0f);
            const float mean = cs * inv;
            const float var  = fmaf(-mean, mean, cq * inv);
            r.x = (v[k].x - mean) * __builtin_amdgcn_rsqf(var + EPS);
        }
        {
            cs += v[k].y; cq = fmaf(v[k].y, v[k].y, cq);
            const float inv  = __builtin_amdgcn_rcpf(nbase + 2.0f);
            const float mean = cs * inv;
            const float var  = fmaf(-mean, mean, cq * inv);
            r.y = (v[k].y - mean) * __builtin_amdgcn_rsqf(var + EPS);
        }
        {
            cs += v[k].z; cq = fmaf(v[k].z, v[k].z, cq);
            const float inv  = __builtin_amdgcn_rcpf(nbase + 3.0f);
            const float mean = cs * inv;
            const float var  = fmaf(-mean, mean, cq * inv);
            r.z = (v[k].z - mean) * __builtin_amdgcn_rsqf(var + EPS);
        }
        {
            cs += v[k].w; cq = fmaf(v[k].w, v[k].w, cq);
            const float inv  = __builtin_amdgcn_rcpf(nbase + 4.0f);
            const float mean = cs * inv;
            const float var  = fmaf(-mean, mean, cq * inv);
            r.w = (v[k].w - mean) * __builtin_amdgcn_rsqf(var + EPS);
        }
        __builtin_nontemporal_store(r, outr + k * TPB + t);
    }
}

extern "C" void kernel_launch(void* const* d_in, const int* in_sizes, int n_in,
                              void* d_out, int out_size, void* d_ws, size_t ws_size,
                              hipStream_t stream) {
    const float* x = (const float*)d_in[0];
    float* out = (float*)d_out;
    const int rows = in_sizes[0] / FRAMES;  // 32*512 = 16384

    cumnorm_kernel<<<dim3(rows), dim3(TPB), 0, stream>>>(x, out, rows);
}